// Round 15
// baseline (498.444 us; speedup 1.0000x reference)
//
#include <hip/hip_runtime.h>
#include <hip/hip_bf16.h>
#include <math.h>

// FEGCL_46127948759594 — E(3)-equivariant GCL on MI355X.
// R15: fuse GEMM3+GEMM4 into one pass over F via concatenated [Wc1|Wq1]
// (NCT=16): halves phase-3/4 activation ds_reads, removes one phase
// boundary, and creates a 64-independent-load burst. launch_bounds(128,2)
// raises VGPR cap to 256 so the allocator can hoist weight loads deep
// (theory: load-ahead depth was VGPR-limited at 76). Rest = R14/R11.

#define N_NODES 50000
#define N_EDGES 800000
#define ASTR 172   // A/H/F row stride in shorts
#define NSTR 204   // node A stride

typedef __attribute__((ext_vector_type(4))) float f32x4;
typedef __attribute__((ext_vector_type(8))) short bf16x8;
typedef __attribute__((ext_vector_type(4))) unsigned short u16x4;
typedef __attribute__((ext_vector_type(8))) unsigned short u16x8;

static __device__ __forceinline__ unsigned short f2bf(float f) {
  return __builtin_bit_cast(unsigned short, __float2bfloat16(f));
}
static __device__ __forceinline__ float bf2f(unsigned short s) {
  unsigned int u = ((unsigned int)s) << 16;
  return __builtin_bit_cast(float, u);
}
static __device__ __forceinline__ float silu_f(float x) {
  return x * __builtin_amdgcn_rcpf(1.0f + __expf(-x));
}
static __device__ __forceinline__ void atomic_pk_add_bf16(unsigned int* addr,
                                                          float lo, float hi) {
  const unsigned int pk = ((unsigned int)f2bf(hi) << 16) | (unsigned int)f2bf(lo);
  asm volatile("global_atomic_pk_add_bf16 %0, %1, off"
               :: "v"((unsigned long long)(uintptr_t)addr), "v"(pk)
               : "memory");
}

// ---------------------------------------------------------------- prep ----
// Swizzle with destination remap: source is [K][NOUT] f32, iterated as
// NCT ct-tiles; destination block index = kt*NCTDST + CTOFF + ct.
static __device__ __forceinline__ void swz_do2(const float* __restrict__ src,
                                               unsigned short* __restrict__ dst,
                                               int K, int NOUT, int NCT,
                                               int NCTDST, int CTOFF, int idx) {
  int lane = idx & 63, blk = idx >> 6;
  int ct = blk % NCT, kt = blk / NCT;
  int col = ct * 16 + (lane & 15);
  int kb = kt * 32 + (lane >> 4) * 8;
  u16x8 o;
  #pragma unroll
  for (int j = 0; j < 8; ++j) {
    int k = kb + j;
    o[j] = (k < K) ? f2bf(src[(size_t)k * NOUT + col]) : (unsigned short)0;
  }
  const int dblk = kt * NCTDST + CTOFF + ct;
  *(u16x8*)(dst + ((size_t)dblk * 64 + lane) * 8) = o;
}
static __device__ __forceinline__ void swz_do(const float* __restrict__ src,
                                              unsigned short* __restrict__ dst,
                                              int K, int NOUT, int NCT, int idx) {
  swz_do2(src, dst, K, NOUT, NCT, NCT, 0, idx);
}

// blocks [0,50): swizzles; [50,832): h->bf16; [832,1687): zero 14MB;
// [1687,4812): edge-row histogram.
__global__ __launch_bounds__(256) void prep1_kernel(
    const float* __restrict__ We1, const float* __restrict__ We2,
    const float* __restrict__ Wc1, const float* __restrict__ Wq1,
    const float* __restrict__ Wn1, const float* __restrict__ Wn2,
    const float* __restrict__ h,
    unsigned short* __restrict__ We1b, unsigned short* __restrict__ We2b,
    unsigned short* __restrict__ Wcqb,
    unsigned short* __restrict__ Wn1b, unsigned short* __restrict__ Wn2b,
    unsigned short* __restrict__ hb, uint4* __restrict__ zbase,
    const int* __restrict__ ei, int* __restrict__ cursor)
{
  const int b = blockIdx.x, t = threadIdx.x;
  if (b < 50) {
    if (b < 10)       swz_do(We1, We1b, 136, 128, 8, b*256 + t);
    else if (b < 18)  swz_do(We2, We2b, 128, 128, 8, (b-10)*256 + t);
    else if (b < 26)  swz_do2(Wc1, Wcqb, 128, 128, 8, 16, 0, (b-18)*256 + t);
    else if (b < 34)  swz_do2(Wq1, Wcqb, 128, 128, 8, 16, 8, (b-26)*256 + t);
    else if (b < 46) { int i = (b-34)*256 + t; if (i < 3072) swz_do(Wn1, Wn1b, 192, 128, 8, i); }
    else              swz_do(Wn2, Wn2b, 128, 64, 4, (b-46)*256 + t);
    return;
  }
  if (b < 832) {                        // h -> bf16, 16 floats/thread
    const int i16 = (b - 50) * 4096 + t * 16;
    if (i16 < N_NODES * 64) {
      u16x8 o0, o1;
      #pragma unroll
      for (int half = 0; half < 2; ++half) {
        f32x4 v0 = *(const f32x4*)(h + i16 + half*8);
        f32x4 v1 = *(const f32x4*)(h + i16 + half*8 + 4);
        #pragma unroll
        for (int i = 0; i < 4; ++i) {
          if (half == 0) { o0[i] = f2bf(v0[i]); o0[i+4] = f2bf(v1[i]); }
          else           { o1[i] = f2bf(v0[i]); o1[i+4] = f2bf(v1[i]); }
        }
      }
      *(u16x8*)(hb + i16) = o0;
      *(u16x8*)(hb + i16 + 8) = o1;
    }
    return;
  }
  if (b < 1687) {                       // zero agg+transS+tanS
    const int i = (b - 832) * 256 + t;
    if (i < 218750) {
      uint4 z; z.x = z.y = z.z = z.w = 0u;
      const int base = i * 4;
      zbase[base+0] = z; zbase[base+1] = z; zbase[base+2] = z; zbase[base+3] = z;
    }
    return;
  }
  const int e = (b - 1687) * 256 + t;   // histogram
  if (e < N_EDGES) atomicAdd(&cursor[ei[e]], 1);
}

__global__ void scan_kernel(int* __restrict__ cursor) {
  __shared__ int s[1024];
  const int t = threadIdx.x;
  const int C = 49;
  const int base = t * C;
  int sum = 0;
  for (int i = 0; i < C; ++i) {
    int n = base + i;
    if (n < N_NODES) sum += cursor[n];
  }
  s[t] = sum;
  __syncthreads();
  for (int d = 1; d < 1024; d <<= 1) {
    int v = (t >= d) ? s[t - d] : 0;
    __syncthreads();
    s[t] += v;
    __syncthreads();
  }
  int run = s[t] - sum;
  for (int i = 0; i < C; ++i) {
    int n = base + i;
    if (n < N_NODES) {
      int d = cursor[n];
      cursor[n] = run;
      run += d;
    }
  }
}

__global__ void scatter_kernel(const int* __restrict__ ei, int* __restrict__ cursor,
                               int2* __restrict__ rc2) {
  int e = blockIdx.x * blockDim.x + threadIdx.x;
  if (e < N_EDGES) {
    int r = ei[e];
    int pos = atomicAdd(&cursor[r], 1);
    int2 v; v.x = r; v.y = ei[N_EDGES + e];
    rc2[pos] = v;
  }
}

// Dual-group weights-as-A GEMM, bias-initialized accumulators (R11-proven).
template <int KT, int NCT>
static __device__ __forceinline__ void mmW2(const unsigned short* __restrict__ a0,
                                            const unsigned short* __restrict__ a1,
                                            int lk,
                                            const unsigned short* __restrict__ Wb,
                                            const float* __restrict__ bias,
                                            int lane, f32x4* acc0, f32x4* acc1) {
  #pragma unroll
  for (int ct = 0; ct < NCT; ++ct) {
    const f32x4 b = *(const f32x4*)&bias[ct*16 + lk*4];
    acc0[ct] = b; acc1[ct] = b;
  }
  __builtin_amdgcn_s_setprio(1);
  #pragma unroll
  for (int kt = 0; kt < KT; ++kt) {
    bf16x8 x0 = *(const bf16x8*)(a0 + kt*32 + lk*8);
    bf16x8 x1 = *(const bf16x8*)(a1 + kt*32 + lk*8);
    const u16x8* bb = (const u16x8*)Wb + (size_t)(kt*NCT)*64 + lane;
    #pragma unroll
    for (int ct = 0; ct < NCT; ++ct) {
      bf16x8 w = *(const bf16x8*)(bb + (size_t)ct*64);
      acc0[ct] = __builtin_amdgcn_mfma_f32_16x16x32_bf16(w, x0, acc0[ct], 0, 0, 0);
      acc1[ct] = __builtin_amdgcn_mfma_f32_16x16x32_bf16(w, x1, acc1[ct], 0, 0, 0);
    }
  }
  __builtin_amdgcn_s_setprio(0);
}

// ---------------------------------------------------------------- edge ----
// 128 threads = 2 waves; 64 edges/block; wave wv owns rows wv*32..wv*32+31.
// launch_bounds(128,2): VGPR cap 256 -> deep weight-load hoisting.
__global__ __launch_bounds__(128, 2) void edge_kernel(
    const unsigned short* __restrict__ hb,
    const float* __restrict__ coord, const float* __restrict__ quat,
    const int2* __restrict__ rc2,
    const unsigned short* __restrict__ We1b, const unsigned short* __restrict__ We2b,
    const unsigned short* __restrict__ Wcqb,
    const float* __restrict__ be1, const float* __restrict__ be2,
    const float* __restrict__ bc1, const float* __restrict__ wc2,
    const float* __restrict__ bq1, const float* __restrict__ Wq2,
    const float* __restrict__ bq2,
    unsigned int* __restrict__ agg32, float* __restrict__ transS,
    float* __restrict__ tanS)
{
  __shared__ __align__(16) unsigned short AF[64 * ASTR];  // 22016 B

  const int tid = threadIdx.x;
  const int wv = tid >> 6, lane = tid & 63;
  const int lr = lane & 15, lk = lane >> 4;
  const int row0 = wv*32 + lr, row1 = row0 + 16;

  // XCD-chunked bijective swizzle, nb=12500: q=1562, rem=4.
  const int xcd = blockIdx.x & 7, idx = blockIdx.x >> 3;
  const int q = 1562, rem = 4;
  const int bid = (xcd < rem ? xcd*(q+1) : rem*(q+1) + (xcd-rem)*q) + idx;
  const int e0 = bid * 64;

  const int2 p0v = rc2[e0 + row0];
  const int2 p1v = rc2[e0 + row1];
  const int r0 = p0v.x, c0 = p0v.y, r1 = p1v.x, c1 = p1v.y;

  // ---- h staging: pure bf16 copies from hb
  {
    const unsigned short* hs0 = hb + (size_t)(lk < 2 ? r0 : c0) * 64 + (lk & 1) * 32;
    const unsigned short* hs1 = hb + (size_t)(lk < 2 ? r1 : c1) * 64 + (lk & 1) * 32;
    const int cb = lk * 32;
    #pragma unroll
    for (int j = 0; j < 32; j += 4) {
      *(u16x4*)&AF[row0*ASTR + cb + j] = *(const u16x4*)(hs0 + j);
      *(u16x4*)&AF[row1*ASTR + cb + j] = *(const u16x4*)(hs1 + j);
    }
  }
  const float cdx0 = coord[r0*3+0] - coord[c0*3+0];
  const float cdy0 = coord[r0*3+1] - coord[c0*3+1];
  const float cdz0 = coord[r0*3+2] - coord[c0*3+2];
  const float cdx1 = coord[r1*3+0] - coord[c1*3+0];
  const float cdy1 = coord[r1*3+1] - coord[c1*3+1];
  const float cdz1 = coord[r1*3+2] - coord[c1*3+2];
  if (lk < 2) {
    const int gr = lk ? r1 : r0, gc = lk ? c1 : c0, grow = lk ? row1 : row0;
    const float gx = lk ? cdx1 : cdx0, gy = lk ? cdy1 : cdy0, gz = lk ? cdz1 : cdz0;
    const float radial = gx*gx + gy*gy + gz*gz;
    const float nrm = sqrtf(radial) + 1e-8f;
    const f32x4 qr4 = *(const f32x4*)&quat[gr*4];
    const f32x4 qc4 = *(const f32x4*)&quat[gc*4];
    const float qix = -qr4[0], qiy = -qr4[1], qiz = -qr4[2], qiw = qr4[3];
    const float qcx = qc4[0], qcy = qc4[1], qcz = qc4[2], qcw = qc4[3];
    const float qpx = qiw*qcx + qix*qcw + qiy*qcz - qiz*qcy;
    const float qpy = qiw*qcy - qix*qcz + qiy*qcw + qiz*qcx;
    const float qpz = qiw*qcz + qix*qcy - qiy*qcx + qiz*qcw;
    const float qpw = qiw*qcw - qix*qcx - qiy*qcy - qiz*qcz;
    const float rinv = __builtin_amdgcn_rcpf(nrm);
    const float vx = gx*rinv, vy = gy*rinv, vz = gz*rinv;
    const float tx = 2.f*(qiy*vz - qiz*vy);
    const float ty = 2.f*(qiz*vx - qix*vz);
    const float tz = 2.f*(qix*vy - qiy*vx);
    const float ux = -(vx + qiw*tx + (qiy*tz - qiz*ty));
    const float uy = -(vy + qiw*ty + (qiz*tx - qix*tz));
    const float uz = -(vz + qiw*tz + (qix*ty - qiy*tx));
    u16x4 f0, f1;
    f0[0] = f2bf(radial); f0[1] = f2bf(qpx); f0[2] = f2bf(qpy); f0[3] = f2bf(qpz);
    f1[0] = f2bf(qpw);    f1[1] = f2bf(ux);  f1[2] = f2bf(uy);  f1[3] = f2bf(uz);
    *(u16x4*)&AF[grow*ASTR + 128] = f0;
    *(u16x4*)&AF[grow*ASTR + 132] = f1;
    const u16x4 z4 = {0, 0, 0, 0};
    #pragma unroll
    for (int j = 136; j < 160; j += 4) *(u16x4*)&AF[grow*ASTR + j] = z4;
  }

  f32x4 acc0[8], acc1[8];

  // ---- GEMM1: silu(ein @ We1 + be1) -> H (in place; bias in acc init)
  mmW2<5,8>(AF + row0*ASTR, AF + row1*ASTR, lk, We1b, be1, lane, acc0, acc1);
  #pragma unroll
  for (int ct = 0; ct < 8; ++ct) {
    const int ocb = ct*16 + lk*4;
    u16x4 k0, k1;
    #pragma unroll
    for (int i = 0; i < 4; ++i) {
      k0[i] = f2bf(silu_f(acc0[ct][i]));
      k1[i] = f2bf(silu_f(acc1[ct][i]));
    }
    *(u16x4*)&AF[row0*ASTR + ocb] = k0;
    *(u16x4*)&AF[row1*ASTR + ocb] = k1;
  }

  // ---- GEMM2: silu(H @ We2 + be2) -> F (in place)
  mmW2<4,8>(AF + row0*ASTR, AF + row1*ASTR, lk, We2b, be2, lane, acc0, acc1);
  #pragma unroll
  for (int ct = 0; ct < 8; ++ct) {
    const int ocb = ct*16 + lk*4;
    u16x4 k0, k1;
    #pragma unroll
    for (int i = 0; i < 4; ++i) {
      k0[i] = f2bf(silu_f(acc0[ct][i]));
      k1[i] = f2bf(silu_f(acc1[ct][i]));
    }
    *(u16x4*)&AF[row0*ASTR + ocb] = k0;
    *(u16x4*)&AF[row1*ASTR + ocb] = k1;
  }

  // ---- GEMM3+4 fused: F @ [Wc1|Wq1] (NCT=16), one pass over F
  f32x4 accF0[16], accF1[16];
  #pragma unroll
  for (int ct = 0; ct < 16; ++ct) {
    const f32x4 b = (ct < 8) ? *(const f32x4*)&bc1[ct*16 + lk*4]
                             : *(const f32x4*)&bq1[(ct-8)*16 + lk*4];
    accF0[ct] = b; accF1[ct] = b;
  }
  __builtin_amdgcn_s_setprio(1);
  #pragma unroll
  for (int kt = 0; kt < 4; ++kt) {
    bf16x8 x0 = *(const bf16x8*)(AF + row0*ASTR + kt*32 + lk*8);
    bf16x8 x1 = *(const bf16x8*)(AF + row1*ASTR + kt*32 + lk*8);
    const u16x8* bb = (const u16x8*)Wcqb + (size_t)(kt*16)*64 + lane;
    #pragma unroll
    for (int ct = 0; ct < 16; ++ct) {
      bf16x8 w = *(const bf16x8*)(bb + (size_t)ct*64);
      accF0[ct] = __builtin_amdgcn_mfma_f32_16x16x32_bf16(w, x0, accF0[ct], 0, 0, 0);
      accF1[ct] = __builtin_amdgcn_mfma_f32_16x16x32_bf16(w, x1, accF1[ct], 0, 0, 0);
    }
  }
  __builtin_amdgcn_s_setprio(0);

  // epilogue: ct 0..7 -> pcs dot(wc2); ct 8..15 -> 3-vec dot(Wq2)
  float pcs0 = 0.f, pcs1 = 0.f;
  float p00 = 0.f, p10 = 0.f, p20 = 0.f;
  float p01 = 0.f, p11 = 0.f, p21 = 0.f;
  #pragma unroll
  for (int ct = 0; ct < 8; ++ct) {
    const f32x4 w4 = *(const f32x4*)&wc2[ct*16 + lk*4];
    #pragma unroll
    for (int i = 0; i < 4; ++i) {
      pcs0 += silu_f(accF0[ct][i]) * w4[i];
      pcs1 += silu_f(accF1[ct][i]) * w4[i];
    }
  }
  #pragma unroll
  for (int ct = 8; ct < 16; ++ct) {
    const float* wq = &Wq2[((ct-8)*16 + lk*4)*3];
    const f32x4 qa = *(const f32x4*)(wq);
    const f32x4 qb = *(const f32x4*)(wq + 4);
    const f32x4 qc = *(const f32x4*)(wq + 8);
    {
      const float v0 = silu_f(accF0[ct][0]);
      const float v1 = silu_f(accF0[ct][1]);
      const float v2 = silu_f(accF0[ct][2]);
      const float v3 = silu_f(accF0[ct][3]);
      p00 += v0*qa[0] + v1*qa[3] + v2*qb[2] + v3*qc[1];
      p10 += v0*qa[1] + v1*qb[0] + v2*qb[3] + v3*qc[2];
      p20 += v0*qa[2] + v1*qb[1] + v2*qc[0] + v3*qc[3];
    }
    {
      const float v0 = silu_f(accF1[ct][0]);
      const float v1 = silu_f(accF1[ct][1]);
      const float v2 = silu_f(accF1[ct][2]);
      const float v3 = silu_f(accF1[ct][3]);
      p01 += v0*qa[0] + v1*qa[3] + v2*qb[2] + v3*qc[1];
      p11 += v0*qa[1] + v1*qb[0] + v2*qb[3] + v3*qc[2];
      p21 += v0*qa[2] + v1*qb[1] + v2*qc[0] + v3*qc[3];
    }
  }
  pcs0 += __shfl_xor(pcs0, 16);  pcs0 += __shfl_xor(pcs0, 32);
  pcs1 += __shfl_xor(pcs1, 16);  pcs1 += __shfl_xor(pcs1, 32);
  p00 += __shfl_xor(p00, 16);  p00 += __shfl_xor(p00, 32);
  p10 += __shfl_xor(p10, 16);  p10 += __shfl_xor(p10, 32);
  p20 += __shfl_xor(p20, 16);  p20 += __shfl_xor(p20, 32);
  p01 += __shfl_xor(p01, 16);  p01 += __shfl_xor(p01, 32);
  p11 += __shfl_xor(p11, 16);  p11 += __shfl_xor(p11, 32);
  p21 += __shfl_xor(p21, 16);  p21 += __shfl_xor(p21, 32);

  // ---- scalar side: 16-lane segmented scans on lk groups 0..2
  if (lk < 3) {
    #pragma unroll
    for (int g = 0; g < 2; ++g) {
      const int rg = g ? r1 : r0;
      const int rUp = __shfl_up(rg, 1, 16);
      const int rDn = __shfl_down(rg, 1, 16);
      const bool head = (lr == 0) || (rUp != rg);
      const bool tail = (lr == 15) || (rDn != rg);
      const float cdj = (lk == 0) ? (g ? cdx1 : cdx0)
                      : (lk == 1) ? (g ? cdy1 : cdy0) : (g ? cdz1 : cdz0);
      const float pj  = (lk == 0) ? (g ? p01 : p00)
                      : (lk == 1) ? (g ? p11 : p10) : (g ? p21 : p20);
      float v1 = cdj * (g ? pcs1 : pcs0);
      float v2 = pj + bq2[lk];
      int f = head ? 1 : 0;
      #pragma unroll
      for (int d = 1; d < 16; d <<= 1) {
        const float o1 = __shfl_up(v1, d, 16);
        const float o2 = __shfl_up(v2, d, 16);
        const int   of = __shfl_up(f,  d, 16);
        if (lr >= d) {
          if (!f) { v1 += o1; v2 += o2; }
          f |= of;
        }
      }
      if (tail) {
        atomicAdd(&transS[rg*3 + lk], v1);
        atomicAdd(&tanS[rg*3 + lk], v2);
      }
    }
  }

  // ---- column reduce over the wave's 32 row-sorted edges (readlane + pk_add)
  {
    float rl_ = 0.f, rh_ = 0.f;
    int prev = __builtin_amdgcn_readlane(r0, 0);
    #pragma unroll
    for (int k2 = 0; k2 < 32; ++k2) {
      const int rr = (k2 < 16) ? __builtin_amdgcn_readlane(r0, k2)
                               : __builtin_amdgcn_readlane(r1, k2 - 16);
      if (rr != prev) {
        atomic_pk_add_bf16(&agg32[(size_t)prev*64 + lane], rl_, rh_);
        rl_ = 0.f; rh_ = 0.f; prev = rr;
      }
      const unsigned int u = *(const unsigned int*)&AF[(wv*32 + k2)*ASTR + 2*lane];
      rl_ += bf2f((unsigned short)(u & 0xffffu));
      rh_ += bf2f((unsigned short)(u >> 16));
    }
    atomic_pk_add_bf16(&agg32[(size_t)prev*64 + lane], rl_, rh_);
  }
}

// ---------------------------------------------------------------- node ----
__global__ __launch_bounds__(256, 4) void node_kernel(
    const float* __restrict__ h, const unsigned short* __restrict__ hb,
    const float* __restrict__ coord, const float* __restrict__ quat,
    const unsigned short* __restrict__ aggb, const float* __restrict__ transS,
    const float* __restrict__ tanS, const int* __restrict__ cursor,
    const unsigned short* __restrict__ Wn1b, const unsigned short* __restrict__ Wn2b,
    const float* __restrict__ bn1, const float* __restrict__ bn2,
    float* __restrict__ out_h, float* __restrict__ out_c, float* __restrict__ out_q)
{
  __shared__ unsigned short A_[64][NSTR];
  const int tid = threadIdx.x;
  const int n0 = blockIdx.x * 64;

  {
    const int row = tid >> 2, sub = tid & 3;
    const int n = n0 + row;
    if (n < N_NODES) {
      if (sub < 2) {
        const unsigned short* hp = hb + (size_t)n*64 + sub*32;
        #pragma unroll
        for (int j = 0; j < 32; j += 4)
          *(u16x4*)&A_[row][sub*32 + j] = *(const u16x4*)(hp + j);
      } else {
        const unsigned short* ap = aggb + (size_t)n*128 + (sub - 2)*64;
        #pragma unroll
        for (int j = 0; j < 64; j += 8)
          *(u16x8*)&A_[row][64 + (sub - 2)*64 + j] = *(const u16x8*)(ap + j);
      }
    } else {
      const u16x4 z4 = {0, 0, 0, 0};
      if (sub < 2) {
        #pragma unroll
        for (int j = 0; j < 32; j += 4) *(u16x4*)&A_[row][sub*32 + j] = z4;
      } else {
        #pragma unroll
        for (int j = 0; j < 64; j += 4) *(u16x4*)&A_[row][64 + (sub - 2)*64 + j] = z4;
      }
    }
  }
  __syncthreads();

  const int wv = tid >> 6, lane = tid & 63;
  const int lr = lane & 15, lk = lane >> 4;
  const int nrow = wv*16 + lr;
  f32x4 acc[8];

  {
    #pragma unroll
    for (int ct = 0; ct < 8; ++ct)
      acc[ct] = *(const f32x4*)&bn1[ct*16 + lk*4];
    #pragma unroll
    for (int kt = 0; kt < 6; ++kt) {
      bf16x8 act = *(const bf16x8*)&A_[nrow][kt*32 + lk*8];
      const u16x8* bb = (const u16x8*)Wn1b + (size_t)(kt*8)*64 + lane;
      #pragma unroll
      for (int ct = 0; ct < 8; ++ct) {
        bf16x8 w = *(const bf16x8*)(bb + (size_t)ct*64);
        acc[ct] = __builtin_amdgcn_mfma_f32_16x16x32_bf16(w, act, acc[ct], 0, 0, 0);
      }
    }
  }
  #pragma unroll
  for (int ct = 0; ct < 8; ++ct) {
    const int ocb = ct*16 + lk*4;
    u16x4 pk;
    #pragma unroll
    for (int i = 0; i < 4; ++i) pk[i] = f2bf(silu_f(acc[ct][i]));
    *(u16x4*)&A_[nrow][ocb] = pk;
  }

  f32x4 acc2[4];
  {
    #pragma unroll
    for (int ct = 0; ct < 4; ++ct)
      acc2[ct] = *(const f32x4*)&bn2[ct*16 + lk*4];
    #pragma unroll
    for (int kt = 0; kt < 4; ++kt) {
      bf16x8 act = *(const bf16x8*)&A_[nrow][kt*32 + lk*8];
      const u16x8* bb = (const u16x8*)Wn2b + (size_t)(kt*4)*64 + lane;
      #pragma unroll
      for (int ct = 0; ct < 4; ++ct) {
        bf16x8 w = *(const bf16x8*)(bb + (size_t)ct*64);
        acc2[ct] = __builtin_amdgcn_mfma_f32_16x16x32_bf16(w, act, acc2[ct], 0, 0, 0);
      }
    }
  }
  const int n = n0 + nrow;
  if (n < N_NODES) {
    #pragma unroll
    for (int ct = 0; ct < 4; ++ct) {
      const int ocb = ct*16 + lk*4;
      const f32x4 h4 = *(const f32x4*)&h[(size_t)n*64 + ocb];
      f32x4 o;
      #pragma unroll
      for (int i = 0; i < 4; ++i) o[i] = h4[i] + acc2[ct][i];
      *(f32x4*)&out_h[(size_t)n*64 + ocb] = o;
    }
  }

  if (tid < 64) {
    const int nn = n0 + tid;
    if (nn < N_NODES) {
      const int deg = cursor[nn] - (nn ? cursor[nn-1] : 0);
      const float inv = 1.0f / fmaxf((float)deg, 1.0f);
      out_c[nn*3+0] = coord[nn*3+0] + transS[nn*3+0]*inv;
      out_c[nn*3+1] = coord[nn*3+1] + transS[nn*3+1]*inv;
      out_c[nn*3+2] = coord[nn*3+2] + transS[nn*3+2]*inv;
      const float ix = tanS[nn*3+0]*inv, iy = tanS[nn*3+1]*inv, iz = tanS[nn*3+2]*inv;
      const float rr = sqrtf(ix*ix + iy*iy + iz*iz);
      const float s = sinf(rr) / rr;
      const float rx = ix*s, ry = iy*s, rz = iz*s, rw = cosf(rr);
      const float px = quat[nn*4+0], py = quat[nn*4+1], pz = quat[nn*4+2], pw = quat[nn*4+3];
      out_q[nn*4+0] = pw*rx + px*rw + py*rz - pz*ry;
      out_q[nn*4+1] = pw*ry - px*rz + py*rw + pz*rx;
      out_q[nn*4+2] = pw*rz + px*ry - py*rx + pz*rw;
      out_q[nn*4+3] = pw*rw - px*rx - py*ry - pz*rz;
    }
  }
}

// -------------------------------------------------------------- launch ----
extern "C" void kernel_launch(void* const* d_in, const int* in_sizes, int n_in,
                              void* d_out, int out_size, void* d_ws, size_t ws_size,
                              hipStream_t stream) {
  (void)in_sizes; (void)n_in; (void)out_size; (void)ws_size;
  const float* h     = (const float*)d_in[0];
  const int*   ei    = (const int*)d_in[1];
  const float* coord = (const float*)d_in[2];
  const float* quat  = (const float*)d_in[3];
  const float* We1 = (const float*)d_in[4];  const float* be1 = (const float*)d_in[5];
  const float* We2 = (const float*)d_in[6];  const float* be2 = (const float*)d_in[7];
  const float* Wn1 = (const float*)d_in[8];  const float* bn1 = (const float*)d_in[9];
  const float* Wn2 = (const float*)d_in[10]; const float* bn2 = (const float*)d_in[11];
  const float* Wc1 = (const float*)d_in[12]; const float* bc1 = (const float*)d_in[13];
  const float* wc2 = (const float*)d_in[14];
  const float* Wq1 = (const float*)d_in[15]; const float* bq1 = (const float*)d_in[16];
  const float* Wq2 = (const float*)d_in[17]; const float* bq2 = (const float*)d_in[18];

  // Layout — total ~27.6 MB (R1-proven 28.0 MB envelope).
  char* ws = (char*)d_ws;
  unsigned int* agg32  = (unsigned int*)(ws);           // bf16x2 [N][64]
  unsigned short* aggb = (unsigned short*)(ws);
  float* transS = (float*)(ws + 12800000);
  float* tanS   = (float*)(ws + 13400000);
  int*   cursor = (int*)  (ws + 14200000);
  int2*  rc2    = (int2*) (ws + 14600064);
  unsigned short* We1b = (unsigned short*)(ws + 21000064);
  unsigned short* We2b = We1b + 5*8*64*8;     // +20480 shorts
  unsigned short* Wcqb = We2b + 4*8*64*8;     // +16384 shorts, spans 4*16*64*8
  unsigned short* Wn1b = Wcqb + 4*16*64*8;    // same offset as before
  unsigned short* Wn2b = Wn1b + 6*8*64*8;     // ends 21,204,864
  unsigned short* hb   = (unsigned short*)(ws + 21204864);

  hipMemsetAsync(cursor, 0, 200000, stream);
  prep1_kernel<<<4812, 256, 0, stream>>>(
      We1, We2, Wc1, Wq1, Wn1, Wn2, h,
      We1b, We2b, Wcqb, Wn1b, Wn2b, hb, (uint4*)ws, ei, cursor);
  scan_kernel<<<1, 1024, 0, stream>>>(cursor);
  scatter_kernel<<<(N_EDGES + 255)/256, 256, 0, stream>>>(ei, cursor, rc2);

  edge_kernel<<<N_EDGES/64, 128, 0, stream>>>(
      hb, coord, quat, rc2, We1b, We2b, Wcqb,
      be1, be2, bc1, wc2, bq1, Wq2, bq2, agg32, transS, tanS);

  float* out_h = (float*)d_out;
  float* out_c = out_h + (size_t)N_NODES*64;
  float* out_q = out_c + (size_t)N_NODES*3;
  node_kernel<<<(N_NODES + 63)/64, 256, 0, stream>>>(
      h, hb, coord, quat, aggb, transS, tanS, cursor, Wn1b, Wn2b, bn1, bn2,
      out_h, out_c, out_q);
}

// Round 16
// 462.488 us; speedup vs baseline: 1.0777x; 1.0777x over previous
//
#include <hip/hip_runtime.h>
#include <hip/hip_bf16.h>
#include <math.h>

// FEGCL_46127948759594 — E(3)-equivariant GCL on MI355X.
// R16: restore the empirical optimum (R11/R14 structure, best total 459-463us,
// edge 276us). Bracketing complete: R12 (fewer waves/more ILP) -6%, R13 (more
// waves) -14% via per-XCD L2 overflow, R15 (fused GEMM3+4, VGPR 108) -12% via
// occupancy. ~10 waves/CU x 76 VGPR x 22KB LDS is the knife-edge optimum.

#define N_NODES 50000
#define N_EDGES 800000
#define ASTR 172   // A/H/F row stride in shorts
#define NSTR 204   // node A stride

typedef __attribute__((ext_vector_type(4))) float f32x4;
typedef __attribute__((ext_vector_type(8))) short bf16x8;
typedef __attribute__((ext_vector_type(4))) unsigned short u16x4;
typedef __attribute__((ext_vector_type(8))) unsigned short u16x8;

static __device__ __forceinline__ unsigned short f2bf(float f) {
  return __builtin_bit_cast(unsigned short, __float2bfloat16(f));
}
static __device__ __forceinline__ float bf2f(unsigned short s) {
  unsigned int u = ((unsigned int)s) << 16;
  return __builtin_bit_cast(float, u);
}
static __device__ __forceinline__ float silu_f(float x) {
  return x * __builtin_amdgcn_rcpf(1.0f + __expf(-x));
}
static __device__ __forceinline__ void atomic_pk_add_bf16(unsigned int* addr,
                                                          float lo, float hi) {
  const unsigned int pk = ((unsigned int)f2bf(hi) << 16) | (unsigned int)f2bf(lo);
  asm volatile("global_atomic_pk_add_bf16 %0, %1, off"
               :: "v"((unsigned long long)(uintptr_t)addr), "v"(pk)
               : "memory");
}

// ---------------------------------------------------------------- prep ----
static __device__ __forceinline__ void swz_do(const float* __restrict__ src,
                                              unsigned short* __restrict__ dst,
                                              int K, int NOUT, int NCT, int idx) {
  int lane = idx & 63, blk = idx >> 6;
  int ct = blk % NCT, kt = blk / NCT;
  int col = ct * 16 + (lane & 15);
  int kb = kt * 32 + (lane >> 4) * 8;
  u16x8 o;
  #pragma unroll
  for (int j = 0; j < 8; ++j) {
    int k = kb + j;
    o[j] = (k < K) ? f2bf(src[(size_t)k * NOUT + col]) : (unsigned short)0;
  }
  *(u16x8*)(dst + (size_t)idx * 8) = o;
}

// blocks [0,50): swizzles; [50,832): h->bf16 (64B/thread);
// [832,1687): zero 14MB (64B/thread); [1687,4812): edge-row histogram.
__global__ __launch_bounds__(256) void prep1_kernel(
    const float* __restrict__ We1, const float* __restrict__ We2,
    const float* __restrict__ Wc1, const float* __restrict__ Wq1,
    const float* __restrict__ Wn1, const float* __restrict__ Wn2,
    const float* __restrict__ h,
    unsigned short* __restrict__ We1b, unsigned short* __restrict__ We2b,
    unsigned short* __restrict__ Wc1b, unsigned short* __restrict__ Wq1b,
    unsigned short* __restrict__ Wn1b, unsigned short* __restrict__ Wn2b,
    unsigned short* __restrict__ hb, uint4* __restrict__ zbase,
    const int* __restrict__ ei, int* __restrict__ cursor)
{
  const int b = blockIdx.x, t = threadIdx.x;
  if (b < 50) {
    if (b < 10)       swz_do(We1, We1b, 136, 128, 8, b*256 + t);
    else if (b < 18)  swz_do(We2, We2b, 128, 128, 8, (b-10)*256 + t);
    else if (b < 26)  swz_do(Wc1, Wc1b, 128, 128, 8, (b-18)*256 + t);
    else if (b < 34)  swz_do(Wq1, Wq1b, 128, 128, 8, (b-26)*256 + t);
    else if (b < 46) { int i = (b-34)*256 + t; if (i < 3072) swz_do(Wn1, Wn1b, 192, 128, 8, i); }
    else              swz_do(Wn2, Wn2b, 128, 64, 4, (b-46)*256 + t);
    return;
  }
  if (b < 832) {                        // h -> bf16, 16 floats/thread
    const int i16 = (b - 50) * 4096 + t * 16;
    if (i16 < N_NODES * 64) {
      u16x8 o0, o1;
      #pragma unroll
      for (int half = 0; half < 2; ++half) {
        f32x4 v0 = *(const f32x4*)(h + i16 + half*8);
        f32x4 v1 = *(const f32x4*)(h + i16 + half*8 + 4);
        #pragma unroll
        for (int i = 0; i < 4; ++i) {
          if (half == 0) { o0[i] = f2bf(v0[i]); o0[i+4] = f2bf(v1[i]); }
          else           { o1[i] = f2bf(v0[i]); o1[i+4] = f2bf(v1[i]); }
        }
      }
      *(u16x8*)(hb + i16) = o0;
      *(u16x8*)(hb + i16 + 8) = o1;
    }
    return;
  }
  if (b < 1687) {                       // zero agg+transS+tanS, 4 uint4/thread
    const int i = (b - 832) * 256 + t;
    if (i < 218750) {
      uint4 z; z.x = z.y = z.z = z.w = 0u;
      const int base = i * 4;
      zbase[base+0] = z; zbase[base+1] = z; zbase[base+2] = z; zbase[base+3] = z;
    }
    return;
  }
  const int e = (b - 1687) * 256 + t;   // histogram
  if (e < N_EDGES) atomicAdd(&cursor[ei[e]], 1);
}

__global__ void scan_kernel(int* __restrict__ cursor) {
  __shared__ int s[1024];
  const int t = threadIdx.x;
  const int C = 49;
  const int base = t * C;
  int sum = 0;
  for (int i = 0; i < C; ++i) {
    int n = base + i;
    if (n < N_NODES) sum += cursor[n];
  }
  s[t] = sum;
  __syncthreads();
  for (int d = 1; d < 1024; d <<= 1) {
    int v = (t >= d) ? s[t - d] : 0;
    __syncthreads();
    s[t] += v;
    __syncthreads();
  }
  int run = s[t] - sum;
  for (int i = 0; i < C; ++i) {
    int n = base + i;
    if (n < N_NODES) {
      int d = cursor[n];
      cursor[n] = run;
      run += d;
    }
  }
}

__global__ void scatter_kernel(const int* __restrict__ ei, int* __restrict__ cursor,
                               int2* __restrict__ rc2) {
  int e = blockIdx.x * blockDim.x + threadIdx.x;
  if (e < N_EDGES) {
    int r = ei[e];
    int pos = atomicAdd(&cursor[r], 1);
    int2 v; v.x = r; v.y = ei[N_EDGES + e];
    rc2[pos] = v;
  }
}

// Dual-group weights-as-A GEMM, bias-initialized accumulators (R11-proven).
template <int KT, int NCT>
static __device__ __forceinline__ void mmW2(const unsigned short* __restrict__ a0,
                                            const unsigned short* __restrict__ a1,
                                            int lk,
                                            const unsigned short* __restrict__ Wb,
                                            const float* __restrict__ bias,
                                            int lane, f32x4* acc0, f32x4* acc1) {
  #pragma unroll
  for (int ct = 0; ct < NCT; ++ct) {
    const f32x4 b = *(const f32x4*)&bias[ct*16 + lk*4];
    acc0[ct] = b; acc1[ct] = b;
  }
  __builtin_amdgcn_s_setprio(1);
  #pragma unroll
  for (int kt = 0; kt < KT; ++kt) {
    bf16x8 x0 = *(const bf16x8*)(a0 + kt*32 + lk*8);
    bf16x8 x1 = *(const bf16x8*)(a1 + kt*32 + lk*8);
    const u16x8* bb = (const u16x8*)Wb + (size_t)(kt*NCT)*64 + lane;
    #pragma unroll
    for (int ct = 0; ct < NCT; ++ct) {
      bf16x8 w = *(const bf16x8*)(bb + (size_t)ct*64);
      acc0[ct] = __builtin_amdgcn_mfma_f32_16x16x32_bf16(w, x0, acc0[ct], 0, 0, 0);
      acc1[ct] = __builtin_amdgcn_mfma_f32_16x16x32_bf16(w, x1, acc1[ct], 0, 0, 0);
    }
  }
  __builtin_amdgcn_s_setprio(0);
}

// ---------------------------------------------------------------- edge ----
// 128 threads = 2 waves; 64 edges/block; wave wv owns rows wv*32..wv*32+31.
__global__ __launch_bounds__(128, 3) void edge_kernel(
    const unsigned short* __restrict__ hb,
    const float* __restrict__ coord, const float* __restrict__ quat,
    const int2* __restrict__ rc2,
    const unsigned short* __restrict__ We1b, const unsigned short* __restrict__ We2b,
    const unsigned short* __restrict__ Wc1b, const unsigned short* __restrict__ Wq1b,
    const float* __restrict__ be1, const float* __restrict__ be2,
    const float* __restrict__ bc1, const float* __restrict__ wc2,
    const float* __restrict__ bq1, const float* __restrict__ Wq2,
    const float* __restrict__ bq2,
    unsigned int* __restrict__ agg32, float* __restrict__ transS,
    float* __restrict__ tanS)
{
  __shared__ __align__(16) unsigned short AF[64 * ASTR];  // 22016 B

  const int tid = threadIdx.x;
  const int wv = tid >> 6, lane = tid & 63;
  const int lr = lane & 15, lk = lane >> 4;
  const int row0 = wv*32 + lr, row1 = row0 + 16;

  // XCD-chunked bijective swizzle, nb=12500: q=1562, rem=4.
  const int xcd = blockIdx.x & 7, idx = blockIdx.x >> 3;
  const int q = 1562, rem = 4;
  const int bid = (xcd < rem ? xcd*(q+1) : rem*(q+1) + (xcd-rem)*q) + idx;
  const int e0 = bid * 64;

  const int2 p0v = rc2[e0 + row0];
  const int2 p1v = rc2[e0 + row1];
  const int r0 = p0v.x, c0 = p0v.y, r1 = p1v.x, c1 = p1v.y;

  // ---- h staging: pure bf16 copies from hb
  {
    const unsigned short* hs0 = hb + (size_t)(lk < 2 ? r0 : c0) * 64 + (lk & 1) * 32;
    const unsigned short* hs1 = hb + (size_t)(lk < 2 ? r1 : c1) * 64 + (lk & 1) * 32;
    const int cb = lk * 32;
    #pragma unroll
    for (int j = 0; j < 32; j += 4) {
      *(u16x4*)&AF[row0*ASTR + cb + j] = *(const u16x4*)(hs0 + j);
      *(u16x4*)&AF[row1*ASTR + cb + j] = *(const u16x4*)(hs1 + j);
    }
  }
  const float cdx0 = coord[r0*3+0] - coord[c0*3+0];
  const float cdy0 = coord[r0*3+1] - coord[c0*3+1];
  const float cdz0 = coord[r0*3+2] - coord[c0*3+2];
  const float cdx1 = coord[r1*3+0] - coord[c1*3+0];
  const float cdy1 = coord[r1*3+1] - coord[c1*3+1];
  const float cdz1 = coord[r1*3+2] - coord[c1*3+2];
  if (lk < 2) {
    const int gr = lk ? r1 : r0, gc = lk ? c1 : c0, grow = lk ? row1 : row0;
    const float gx = lk ? cdx1 : cdx0, gy = lk ? cdy1 : cdy0, gz = lk ? cdz1 : cdz0;
    const float radial = gx*gx + gy*gy + gz*gz;
    const float nrm = sqrtf(radial) + 1e-8f;
    const f32x4 qr4 = *(const f32x4*)&quat[gr*4];
    const f32x4 qc4 = *(const f32x4*)&quat[gc*4];
    const float qix = -qr4[0], qiy = -qr4[1], qiz = -qr4[2], qiw = qr4[3];
    const float qcx = qc4[0], qcy = qc4[1], qcz = qc4[2], qcw = qc4[3];
    const float qpx = qiw*qcx + qix*qcw + qiy*qcz - qiz*qcy;
    const float qpy = qiw*qcy - qix*qcz + qiy*qcw + qiz*qcx;
    const float qpz = qiw*qcz + qix*qcy - qiy*qcx + qiz*qcw;
    const float qpw = qiw*qcw - qix*qcx - qiy*qcy - qiz*qcz;
    const float rinv = __builtin_amdgcn_rcpf(nrm);
    const float vx = gx*rinv, vy = gy*rinv, vz = gz*rinv;
    const float tx = 2.f*(qiy*vz - qiz*vy);
    const float ty = 2.f*(qiz*vx - qix*vz);
    const float tz = 2.f*(qix*vy - qiy*vx);
    const float ux = -(vx + qiw*tx + (qiy*tz - qiz*ty));
    const float uy = -(vy + qiw*ty + (qiz*tx - qix*tz));
    const float uz = -(vz + qiw*tz + (qix*ty - qiy*tx));
    u16x4 f0, f1;
    f0[0] = f2bf(radial); f0[1] = f2bf(qpx); f0[2] = f2bf(qpy); f0[3] = f2bf(qpz);
    f1[0] = f2bf(qpw);    f1[1] = f2bf(ux);  f1[2] = f2bf(uy);  f1[3] = f2bf(uz);
    *(u16x4*)&AF[grow*ASTR + 128] = f0;
    *(u16x4*)&AF[grow*ASTR + 132] = f1;
    const u16x4 z4 = {0, 0, 0, 0};
    #pragma unroll
    for (int j = 136; j < 160; j += 4) *(u16x4*)&AF[grow*ASTR + j] = z4;
  }

  f32x4 acc0[8], acc1[8];

  // ---- GEMM1: silu(ein @ We1 + be1) -> H (in place; bias in acc init)
  mmW2<5,8>(AF + row0*ASTR, AF + row1*ASTR, lk, We1b, be1, lane, acc0, acc1);
  #pragma unroll
  for (int ct = 0; ct < 8; ++ct) {
    const int ocb = ct*16 + lk*4;
    u16x4 k0, k1;
    #pragma unroll
    for (int i = 0; i < 4; ++i) {
      k0[i] = f2bf(silu_f(acc0[ct][i]));
      k1[i] = f2bf(silu_f(acc1[ct][i]));
    }
    *(u16x4*)&AF[row0*ASTR + ocb] = k0;
    *(u16x4*)&AF[row1*ASTR + ocb] = k1;
  }

  // ---- GEMM2: silu(H @ We2 + be2) -> F (in place)
  mmW2<4,8>(AF + row0*ASTR, AF + row1*ASTR, lk, We2b, be2, lane, acc0, acc1);
  #pragma unroll
  for (int ct = 0; ct < 8; ++ct) {
    const int ocb = ct*16 + lk*4;
    u16x4 k0, k1;
    #pragma unroll
    for (int i = 0; i < 4; ++i) {
      k0[i] = f2bf(silu_f(acc0[ct][i]));
      k1[i] = f2bf(silu_f(acc1[ct][i]));
    }
    *(u16x4*)&AF[row0*ASTR + ocb] = k0;
    *(u16x4*)&AF[row1*ASTR + ocb] = k1;
  }

  // ---- GEMM3: (silu(F @ Wc1 + bc1)) . wc2
  float pcs0 = 0.f, pcs1 = 0.f;
  mmW2<4,8>(AF + row0*ASTR, AF + row1*ASTR, lk, Wc1b, bc1, lane, acc0, acc1);
  #pragma unroll
  for (int ct = 0; ct < 8; ++ct) {
    const f32x4 w4 = *(const f32x4*)&wc2[ct*16 + lk*4];
    #pragma unroll
    for (int i = 0; i < 4; ++i) {
      pcs0 += silu_f(acc0[ct][i]) * w4[i];
      pcs1 += silu_f(acc1[ct][i]) * w4[i];
    }
  }
  pcs0 += __shfl_xor(pcs0, 16);  pcs0 += __shfl_xor(pcs0, 32);
  pcs1 += __shfl_xor(pcs1, 16);  pcs1 += __shfl_xor(pcs1, 32);

  // ---- GEMM4: silu(F @ Wq1 + bq1) @ Wq2
  float p00 = 0.f, p10 = 0.f, p20 = 0.f;
  float p01 = 0.f, p11 = 0.f, p21 = 0.f;
  mmW2<4,8>(AF + row0*ASTR, AF + row1*ASTR, lk, Wq1b, bq1, lane, acc0, acc1);
  #pragma unroll
  for (int ct = 0; ct < 8; ++ct) {
    const float* wq = &Wq2[(ct*16 + lk*4)*3];
    const f32x4 qa = *(const f32x4*)(wq);
    const f32x4 qb = *(const f32x4*)(wq + 4);
    const f32x4 qc = *(const f32x4*)(wq + 8);
    {
      const float v0 = silu_f(acc0[ct][0]);
      const float v1 = silu_f(acc0[ct][1]);
      const float v2 = silu_f(acc0[ct][2]);
      const float v3 = silu_f(acc0[ct][3]);
      p00 += v0*qa[0] + v1*qa[3] + v2*qb[2] + v3*qc[1];
      p10 += v0*qa[1] + v1*qb[0] + v2*qb[3] + v3*qc[2];
      p20 += v0*qa[2] + v1*qb[1] + v2*qc[0] + v3*qc[3];
    }
    {
      const float v0 = silu_f(acc1[ct][0]);
      const float v1 = silu_f(acc1[ct][1]);
      const float v2 = silu_f(acc1[ct][2]);
      const float v3 = silu_f(acc1[ct][3]);
      p01 += v0*qa[0] + v1*qa[3] + v2*qb[2] + v3*qc[1];
      p11 += v0*qa[1] + v1*qb[0] + v2*qb[3] + v3*qc[2];
      p21 += v0*qa[2] + v1*qb[1] + v2*qc[0] + v3*qc[3];
    }
  }
  p00 += __shfl_xor(p00, 16);  p00 += __shfl_xor(p00, 32);
  p10 += __shfl_xor(p10, 16);  p10 += __shfl_xor(p10, 32);
  p20 += __shfl_xor(p20, 16);  p20 += __shfl_xor(p20, 32);
  p01 += __shfl_xor(p01, 16);  p01 += __shfl_xor(p01, 32);
  p11 += __shfl_xor(p11, 16);  p11 += __shfl_xor(p11, 32);
  p21 += __shfl_xor(p21, 16);  p21 += __shfl_xor(p21, 32);

  // ---- scalar side: 16-lane segmented scans on lk groups 0..2
  if (lk < 3) {
    #pragma unroll
    for (int g = 0; g < 2; ++g) {
      const int rg = g ? r1 : r0;
      const int rUp = __shfl_up(rg, 1, 16);
      const int rDn = __shfl_down(rg, 1, 16);
      const bool head = (lr == 0) || (rUp != rg);
      const bool tail = (lr == 15) || (rDn != rg);
      const float cdj = (lk == 0) ? (g ? cdx1 : cdx0)
                      : (lk == 1) ? (g ? cdy1 : cdy0) : (g ? cdz1 : cdz0);
      const float pj  = (lk == 0) ? (g ? p01 : p00)
                      : (lk == 1) ? (g ? p11 : p10) : (g ? p21 : p20);
      float v1 = cdj * (g ? pcs1 : pcs0);
      float v2 = pj + bq2[lk];
      int f = head ? 1 : 0;
      #pragma unroll
      for (int d = 1; d < 16; d <<= 1) {
        const float o1 = __shfl_up(v1, d, 16);
        const float o2 = __shfl_up(v2, d, 16);
        const int   of = __shfl_up(f,  d, 16);
        if (lr >= d) {
          if (!f) { v1 += o1; v2 += o2; }
          f |= of;
        }
      }
      if (tail) {
        atomicAdd(&transS[rg*3 + lk], v1);
        atomicAdd(&tanS[rg*3 + lk], v2);
      }
    }
  }

  // ---- column reduce over the wave's 32 row-sorted edges (readlane + pk_add)
  {
    float rl_ = 0.f, rh_ = 0.f;
    int prev = __builtin_amdgcn_readlane(r0, 0);
    #pragma unroll
    for (int k2 = 0; k2 < 32; ++k2) {
      const int rr = (k2 < 16) ? __builtin_amdgcn_readlane(r0, k2)
                               : __builtin_amdgcn_readlane(r1, k2 - 16);
      if (rr != prev) {
        atomic_pk_add_bf16(&agg32[(size_t)prev*64 + lane], rl_, rh_);
        rl_ = 0.f; rh_ = 0.f; prev = rr;
      }
      const unsigned int u = *(const unsigned int*)&AF[(wv*32 + k2)*ASTR + 2*lane];
      rl_ += bf2f((unsigned short)(u & 0xffffu));
      rh_ += bf2f((unsigned short)(u >> 16));
    }
    atomic_pk_add_bf16(&agg32[(size_t)prev*64 + lane], rl_, rh_);
  }
}

// ---------------------------------------------------------------- node ----
__global__ __launch_bounds__(256, 4) void node_kernel(
    const float* __restrict__ h, const unsigned short* __restrict__ hb,
    const float* __restrict__ coord, const float* __restrict__ quat,
    const unsigned short* __restrict__ aggb, const float* __restrict__ transS,
    const float* __restrict__ tanS, const int* __restrict__ cursor,
    const unsigned short* __restrict__ Wn1b, const unsigned short* __restrict__ Wn2b,
    const float* __restrict__ bn1, const float* __restrict__ bn2,
    float* __restrict__ out_h, float* __restrict__ out_c, float* __restrict__ out_q)
{
  __shared__ unsigned short A_[64][NSTR];
  const int tid = threadIdx.x;
  const int n0 = blockIdx.x * 64;

  {
    const int row = tid >> 2, sub = tid & 3;
    const int n = n0 + row;
    if (n < N_NODES) {
      if (sub < 2) {
        const unsigned short* hp = hb + (size_t)n*64 + sub*32;
        #pragma unroll
        for (int j = 0; j < 32; j += 4)
          *(u16x4*)&A_[row][sub*32 + j] = *(const u16x4*)(hp + j);
      } else {
        const unsigned short* ap = aggb + (size_t)n*128 + (sub - 2)*64;
        #pragma unroll
        for (int j = 0; j < 64; j += 8)
          *(u16x8*)&A_[row][64 + (sub - 2)*64 + j] = *(const u16x8*)(ap + j);
      }
    } else {
      const u16x4 z4 = {0, 0, 0, 0};
      if (sub < 2) {
        #pragma unroll
        for (int j = 0; j < 32; j += 4) *(u16x4*)&A_[row][sub*32 + j] = z4;
      } else {
        #pragma unroll
        for (int j = 0; j < 64; j += 4) *(u16x4*)&A_[row][64 + (sub - 2)*64 + j] = z4;
      }
    }
  }
  __syncthreads();

  const int wv = tid >> 6, lane = tid & 63;
  const int lr = lane & 15, lk = lane >> 4;
  const int nrow = wv*16 + lr;
  f32x4 acc[8];

  {
    #pragma unroll
    for (int ct = 0; ct < 8; ++ct)
      acc[ct] = *(const f32x4*)&bn1[ct*16 + lk*4];
    #pragma unroll
    for (int kt = 0; kt < 6; ++kt) {
      bf16x8 act = *(const bf16x8*)&A_[nrow][kt*32 + lk*8];
      const u16x8* bb = (const u16x8*)Wn1b + (size_t)(kt*8)*64 + lane;
      #pragma unroll
      for (int ct = 0; ct < 8; ++ct) {
        bf16x8 w = *(const bf16x8*)(bb + (size_t)ct*64);
        acc[ct] = __builtin_amdgcn_mfma_f32_16x16x32_bf16(w, act, acc[ct], 0, 0, 0);
      }
    }
  }
  #pragma unroll
  for (int ct = 0; ct < 8; ++ct) {
    const int ocb = ct*16 + lk*4;
    u16x4 pk;
    #pragma unroll
    for (int i = 0; i < 4; ++i) pk[i] = f2bf(silu_f(acc[ct][i]));
    *(u16x4*)&A_[nrow][ocb] = pk;
  }

  f32x4 acc2[4];
  {
    #pragma unroll
    for (int ct = 0; ct < 4; ++ct)
      acc2[ct] = *(const f32x4*)&bn2[ct*16 + lk*4];
    #pragma unroll
    for (int kt = 0; kt < 4; ++kt) {
      bf16x8 act = *(const bf16x8*)&A_[nrow][kt*32 + lk*8];
      const u16x8* bb = (const u16x8*)Wn2b + (size_t)(kt*4)*64 + lane;
      #pragma unroll
      for (int ct = 0; ct < 4; ++ct) {
        bf16x8 w = *(const bf16x8*)(bb + (size_t)ct*64);
        acc2[ct] = __builtin_amdgcn_mfma_f32_16x16x32_bf16(w, act, acc2[ct], 0, 0, 0);
      }
    }
  }
  const int n = n0 + nrow;
  if (n < N_NODES) {
    #pragma unroll
    for (int ct = 0; ct < 4; ++ct) {
      const int ocb = ct*16 + lk*4;
      const f32x4 h4 = *(const f32x4*)&h[(size_t)n*64 + ocb];
      f32x4 o;
      #pragma unroll
      for (int i = 0; i < 4; ++i) o[i] = h4[i] + acc2[ct][i];
      *(f32x4*)&out_h[(size_t)n*64 + ocb] = o;
    }
  }

  if (tid < 64) {
    const int nn = n0 + tid;
    if (nn < N_NODES) {
      const int deg = cursor[nn] - (nn ? cursor[nn-1] : 0);
      const float inv = 1.0f / fmaxf((float)deg, 1.0f);
      out_c[nn*3+0] = coord[nn*3+0] + transS[nn*3+0]*inv;
      out_c[nn*3+1] = coord[nn*3+1] + transS[nn*3+1]*inv;
      out_c[nn*3+2] = coord[nn*3+2] + transS[nn*3+2]*inv;
      const float ix = tanS[nn*3+0]*inv, iy = tanS[nn*3+1]*inv, iz = tanS[nn*3+2]*inv;
      const float rr = sqrtf(ix*ix + iy*iy + iz*iz);
      const float s = sinf(rr) / rr;
      const float rx = ix*s, ry = iy*s, rz = iz*s, rw = cosf(rr);
      const float px = quat[nn*4+0], py = quat[nn*4+1], pz = quat[nn*4+2], pw = quat[nn*4+3];
      out_q[nn*4+0] = pw*rx + px*rw + py*rz - pz*ry;
      out_q[nn*4+1] = pw*ry - px*rz + py*rw + pz*rx;
      out_q[nn*4+2] = pw*rz + px*ry - py*rx + pz*rw;
      out_q[nn*4+3] = pw*rw - px*rx - py*ry - pz*rz;
    }
  }
}

// -------------------------------------------------------------- launch ----
extern "C" void kernel_launch(void* const* d_in, const int* in_sizes, int n_in,
                              void* d_out, int out_size, void* d_ws, size_t ws_size,
                              hipStream_t stream) {
  (void)in_sizes; (void)n_in; (void)out_size; (void)ws_size;
  const float* h     = (const float*)d_in[0];
  const int*   ei    = (const int*)d_in[1];
  const float* coord = (const float*)d_in[2];
  const float* quat  = (const float*)d_in[3];
  const float* We1 = (const float*)d_in[4];  const float* be1 = (const float*)d_in[5];
  const float* We2 = (const float*)d_in[6];  const float* be2 = (const float*)d_in[7];
  const float* Wn1 = (const float*)d_in[8];  const float* bn1 = (const float*)d_in[9];
  const float* Wn2 = (const float*)d_in[10]; const float* bn2 = (const float*)d_in[11];
  const float* Wc1 = (const float*)d_in[12]; const float* bc1 = (const float*)d_in[13];
  const float* wc2 = (const float*)d_in[14];
  const float* Wq1 = (const float*)d_in[15]; const float* bq1 = (const float*)d_in[16];
  const float* Wq2 = (const float*)d_in[17]; const float* bq2 = (const float*)d_in[18];

  // Layout — total ~27.6 MB (R1-proven 28.0 MB envelope).
  char* ws = (char*)d_ws;
  unsigned int* agg32  = (unsigned int*)(ws);           // bf16x2 [N][64]
  unsigned short* aggb = (unsigned short*)(ws);
  float* transS = (float*)(ws + 12800000);
  float* tanS   = (float*)(ws + 13400000);
  int*   cursor = (int*)  (ws + 14200000);
  int2*  rc2    = (int2*) (ws + 14600064);
  unsigned short* We1b = (unsigned short*)(ws + 21000064);
  unsigned short* We2b = We1b + 5*8*64*8;
  unsigned short* Wc1b = We2b + 4*8*64*8;
  unsigned short* Wq1b = Wc1b + 4*8*64*8;
  unsigned short* Wn1b = Wq1b + 4*8*64*8;
  unsigned short* Wn2b = Wn1b + 6*8*64*8;               // ends 21,204,864
  unsigned short* hb   = (unsigned short*)(ws + 21204864);

  hipMemsetAsync(cursor, 0, 200000, stream);
  prep1_kernel<<<4812, 256, 0, stream>>>(
      We1, We2, Wc1, Wq1, Wn1, Wn2, h,
      We1b, We2b, Wc1b, Wq1b, Wn1b, Wn2b, hb, (uint4*)ws, ei, cursor);
  scan_kernel<<<1, 1024, 0, stream>>>(cursor);
  scatter_kernel<<<(N_EDGES + 255)/256, 256, 0, stream>>>(ei, cursor, rc2);

  edge_kernel<<<N_EDGES/64, 128, 0, stream>>>(
      hb, coord, quat, rc2, We1b, We2b, Wc1b, Wq1b,
      be1, be2, bc1, wc2, bq1, Wq2, bq2, agg32, transS, tanS);

  float* out_h = (float*)d_out;
  float* out_c = out_h + (size_t)N_NODES*64;
  float* out_q = out_c + (size_t)N_NODES*3;
  node_kernel<<<(N_NODES + 63)/64, 256, 0, stream>>>(
      h, hb, coord, quat, aggb, transS, tanS, cursor, Wn1b, Wn2b, bn1, bn2,
      out_h, out_c, out_q);
}